// Round 2
// baseline (43357.062 us; speedup 1.0000x reference)
//
#include <hip/hip_runtime.h>
#include <math.h>

// ---------------------------------------------------------------------------
// K/V projection precompute (fp32 SGEMM):
//   out[b][h][m][d] = sum_c mem[m,b,c] * W[h*64+d, c] + bias[h*64+d]
// grid: jt(8) + 8*(mt(8) + 8*b(128)); block 256 = 16x16 threads, 4x4 out each
// ---------------------------------------------------------------------------
__global__ __launch_bounds__(256) void kv_proj(
    const float* __restrict__ mem, const float* __restrict__ W,
    const float* __restrict__ bias, float* __restrict__ outp) {
  __shared__ float As[32][68];  // [k][m], pad 68 keeps float4 16B-aligned
  __shared__ float Bs[32][68];  // [k][j]
  int gid = blockIdx.x;
  int jt = gid & 7, mt = (gid >> 3) & 7, b = gid >> 6;
  int t = threadIdx.x;
  int lm = t >> 2;           // 0..63 staging row
  int kq = (t & 3) * 8;      // 0,8,16,24
  int tx = t & 15, ty = t >> 4;
  float acc[4][4];
  #pragma unroll
  for (int r = 0; r < 4; ++r)
    #pragma unroll
    for (int c = 0; c < 4; ++c) acc[r][c] = 0.f;
  const float* Arow = mem + (size_t)(mt * 64 + lm) * 65536 + (size_t)b * 512 + kq;
  const float* Brow = W + (size_t)(jt * 64 + lm) * 512 + kq;
  for (int k0 = 0; k0 < 512; k0 += 32) {
    float4 a0 = *(const float4*)(Arow + k0);
    float4 a1 = *(const float4*)(Arow + k0 + 4);
    float4 b0 = *(const float4*)(Brow + k0);
    float4 b1 = *(const float4*)(Brow + k0 + 4);
    As[kq + 0][lm] = a0.x; As[kq + 1][lm] = a0.y; As[kq + 2][lm] = a0.z; As[kq + 3][lm] = a0.w;
    As[kq + 4][lm] = a1.x; As[kq + 5][lm] = a1.y; As[kq + 6][lm] = a1.z; As[kq + 7][lm] = a1.w;
    Bs[kq + 0][lm] = b0.x; Bs[kq + 1][lm] = b0.y; Bs[kq + 2][lm] = b0.z; Bs[kq + 3][lm] = b0.w;
    Bs[kq + 4][lm] = b1.x; Bs[kq + 5][lm] = b1.y; Bs[kq + 6][lm] = b1.z; Bs[kq + 7][lm] = b1.w;
    __syncthreads();
    #pragma unroll
    for (int k = 0; k < 32; ++k) {
      float4 av = *(const float4*)&As[k][ty * 4];
      float4 bv = *(const float4*)&Bs[k][tx * 4];
      float ar[4] = {av.x, av.y, av.z, av.w};
      float br[4] = {bv.x, bv.y, bv.z, bv.w};
      #pragma unroll
      for (int r = 0; r < 4; ++r)
        #pragma unroll
        for (int c = 0; c < 4; ++c) acc[r][c] = fmaf(ar[r], br[c], acc[r][c]);
    }
    __syncthreads();
  }
  float4 bb = *(const float4*)(bias + jt * 64 + tx * 4);
  #pragma unroll
  for (int r = 0; r < 4; ++r) {
    int m = mt * 64 + ty * 4 + r;
    float4 o;
    o.x = acc[r][0] + bb.x; o.y = acc[r][1] + bb.y;
    o.z = acc[r][2] + bb.z; o.w = acc[r][3] + bb.w;
    *(float4*)(outp + (((size_t)b * 8 + jt) * 512 + m) * 64 + tx * 4) = o;
  }
}

// ---------------------------------------------------------------------------
__global__ __launch_bounds__(256) void init_kernel(float* __restrict__ h0,
                                                   unsigned long long* __restrict__ packed) {
  int t = threadIdx.x + blockIdx.x * blockDim.x;
  for (int i = t; i < 128 * 512; i += blockDim.x * gridDim.x) h0[i] = 0.f;
  if (t < 128) packed[t] = (0x80000000ull << 32) | 0xFFFFFFFFull;  // val 0.0, idx 0
}

// ---------------------------------------------------------------------------
// q[b,j] = bq[j] + sum_k [emb[tok_b], h_prev[b]]_k * Wq[j,k]   (k<1024)
// grid 256: bt(16) x jt(16, 32 j each); block 256: 8b x 32j, 1 output/thread
// ---------------------------------------------------------------------------
__global__ __launch_bounds__(256) void q_kernel(
    const float* __restrict__ emb, const float* __restrict__ Wq,
    const float* __restrict__ bq, const unsigned long long* __restrict__ packed,
    const float* __restrict__ h_prev, float* __restrict__ q) {
  __shared__ float act[8][1024];
  __shared__ int toks[8];
  int t = threadIdx.x;
  int bt = blockIdx.x >> 4;
  int jt = blockIdx.x & 15;
  if (t < 8) {
    unsigned long long key = packed[bt * 8 + t];
    toks[t] = (int)(0xFFFFFFFFu - (unsigned int)(key & 0xFFFFFFFFull));
  }
  __syncthreads();
  #pragma unroll
  for (int i = 0; i < 16; ++i) {
    int flat = i * 256 + t;  // coalesced: consecutive t -> consecutive k
    int lb = flat >> 9, k = flat & 511;
    act[lb][k] = emb[(size_t)toks[lb] * 512 + k];
    act[lb][512 + k] = h_prev[(size_t)(bt * 8 + lb) * 512 + k];
  }
  __syncthreads();
  int lb = t >> 5, j = (jt << 5) + (t & 31);
  int b = bt * 8 + lb;
  float acc = bq[j];
  const float* wrow = Wq + (size_t)j * 1024;
  const float* a = act[lb];
  #pragma unroll 8
  for (int k = 0; k < 1024; k += 4) {
    float4 w = *(const float4*)(wrow + k);
    acc = fmaf(a[k + 0], w.x, acc);
    acc = fmaf(a[k + 1], w.y, acc);
    acc = fmaf(a[k + 2], w.z, acc);
    acc = fmaf(a[k + 3], w.w, acc);
  }
  q[(size_t)b * 512 + j] = acc;
}

// ---------------------------------------------------------------------------
// Attention: one block per (b, head). fp32 K/V streamed from HBM.
// ---------------------------------------------------------------------------
__global__ __launch_bounds__(256) void attn_kernel(
    const float* __restrict__ kp, const float* __restrict__ vp,
    const float* __restrict__ q, float* __restrict__ ctx, float* __restrict__ att_buf) {
  int b = blockIdx.x >> 3, hd = blockIdx.x & 7;
  __shared__ float qs[64];
  __shared__ float att[512];
  __shared__ __align__(16) float red[8][64];
  __shared__ float rmax[4], rsum[4];
  int t = threadIdx.x;
  if (t < 64) qs[t] = q[(size_t)b * 512 + hd * 64 + t];
  __syncthreads();
  const float* Kb = kp + (size_t)(b * 8 + hd) * 512 * 64;
  const float* Vb = vp + (size_t)(b * 8 + hd) * 512 * 64;
  float s[2];
  #pragma unroll
  for (int r = 0; r < 2; ++r) {
    int m = t + r * 256;
    const float* krow = Kb + (size_t)m * 64;
    float acc = 0.f;
    #pragma unroll
    for (int i = 0; i < 16; ++i) {
      float4 kk = *(const float4*)(krow + i * 4);
      acc = fmaf(qs[4 * i + 0], kk.x, acc);
      acc = fmaf(qs[4 * i + 1], kk.y, acc);
      acc = fmaf(qs[4 * i + 2], kk.z, acc);
      acc = fmaf(qs[4 * i + 3], kk.w, acc);
    }
    s[r] = acc * 0.125f;  // 1/sqrt(64)
  }
  float mx = fmaxf(s[0], s[1]);
  #pragma unroll
  for (int o = 32; o > 0; o >>= 1) mx = fmaxf(mx, __shfl_xor(mx, o));
  if ((t & 63) == 0) rmax[t >> 6] = mx;
  __syncthreads();
  mx = fmaxf(fmaxf(rmax[0], rmax[1]), fmaxf(rmax[2], rmax[3]));
  float e0 = expf(s[0] - mx), e1 = expf(s[1] - mx);
  float sm = e0 + e1;
  #pragma unroll
  for (int o = 32; o > 0; o >>= 1) sm += __shfl_xor(sm, o);
  if ((t & 63) == 0) rsum[t >> 6] = sm;
  __syncthreads();
  sm = rsum[0] + rsum[1] + rsum[2] + rsum[3];
  float inv = 1.f / sm;
  float a0 = e0 * inv, a1 = e1 * inv;
  att[t] = a0;
  att[t + 256] = a1;
  att_buf[(size_t)(b * 8 + hd) * 512 + t] = a0;
  att_buf[(size_t)(b * 8 + hd) * 512 + t + 256] = a1;
  __syncthreads();
  // ctx: 8 m-chunks of 64; within a chunk 32 threads cover 64 d via float2
  int p = t & 31, ch = t >> 5;
  int d0 = p * 2;
  float c0 = 0.f, c1 = 0.f;
  int m0 = ch * 64;
  #pragma unroll 8
  for (int m = m0; m < m0 + 64; ++m) {
    float2 vv = *(const float2*)(Vb + (size_t)m * 64 + d0);
    float am = att[m];
    c0 = fmaf(am, vv.x, c0);
    c1 = fmaf(am, vv.y, c1);
  }
  *(float2*)&red[ch][d0] = make_float2(c0, c1);
  __syncthreads();
  if (t < 64) {
    float cc = 0.f;
    #pragma unroll
    for (int c2 = 0; c2 < 8; ++c2) cc += red[c2][t];
    ctx[(size_t)b * 512 + hd * 64 + t] = cc;
  }
}

// ---------------------------------------------------------------------------
// GRU + hiddens-out; extra blocks: scores-out (mean over heads) + packed reset
// grid 320: [0,256) GRU (bt16 x jt16), [256,320) scores
// ---------------------------------------------------------------------------
__global__ __launch_bounds__(256) void gru_kernel(
    const float* __restrict__ W_ih, const float* __restrict__ W_hh,
    const float* __restrict__ b_ih, const float* __restrict__ b_hh,
    const float* __restrict__ ctx, const float* __restrict__ h_prev,
    float* __restrict__ h_new, const float* __restrict__ att_buf,
    const int* __restrict__ lens, float* __restrict__ out_hid,
    float* __restrict__ out_sc, unsigned long long* __restrict__ packed,
    int step) {
  __shared__ float cs[8][512];
  __shared__ float hs[8][512];
  int bi = blockIdx.x;
  int t = threadIdx.x;
  if (bi >= 256) {
    int sb = bi - 256;  // 0..63
    if (sb == 0 && t < 128) packed[t] = 0ull;  // reset for this step's logits atomics
    #pragma unroll
    for (int i = 0; i < 4; ++i) {
      int flat = sb * 1024 + i * 256 + t;  // over b*512+m
      int bb = flat >> 9, m = flat & 511;
      float sum = 0.f;
      #pragma unroll
      for (int h = 0; h < 8; ++h) sum += att_buf[(size_t)(bb * 8 + h) * 512 + m];
      float val = sum * 0.125f;
      out_sc[(size_t)step * 65536 + flat] = (step < lens[bb]) ? val : 0.f;
    }
    return;
  }
  int bt = bi >> 4, jt = bi & 15;
  #pragma unroll
  for (int i = 0; i < 16; ++i) {
    int flat = i * 256 + t;
    int lb = flat >> 9, k = flat & 511;
    cs[lb][k] = ctx[(size_t)(bt * 8 + lb) * 512 + k];
    hs[lb][k] = h_prev[(size_t)(bt * 8 + lb) * 512 + k];
  }
  __syncthreads();
  int lb = t >> 5, j = (jt << 5) + (t & 31);
  int b = bt * 8 + lb;
  float air = b_ih[j], aiz = b_ih[512 + j], ain = b_ih[1024 + j];
  float ahr = b_hh[j], ahz = b_hh[512 + j], ahn = b_hh[1024 + j];
  const float* c = cs[lb];
  const float* hh = hs[lb];
  const float* wi0 = W_ih + (size_t)j * 512;
  const float* wi1 = W_ih + (size_t)(512 + j) * 512;
  const float* wi2 = W_ih + (size_t)(1024 + j) * 512;
  const float* wh0 = W_hh + (size_t)j * 512;
  const float* wh1 = W_hh + (size_t)(512 + j) * 512;
  const float* wh2 = W_hh + (size_t)(1024 + j) * 512;
  #pragma unroll 2
  for (int k = 0; k < 512; k += 4) {
    float4 wa = *(const float4*)(wi0 + k);
    float4 wb = *(const float4*)(wi1 + k);
    float4 wc = *(const float4*)(wi2 + k);
    float4 wd = *(const float4*)(wh0 + k);
    float4 we = *(const float4*)(wh1 + k);
    float4 wf = *(const float4*)(wh2 + k);
    float c0 = c[k], c1 = c[k + 1], c2 = c[k + 2], c3 = c[k + 3];
    float h0 = hh[k], h1 = hh[k + 1], h2 = hh[k + 2], h3 = hh[k + 3];
    air = fmaf(c0, wa.x, air); air = fmaf(c1, wa.y, air); air = fmaf(c2, wa.z, air); air = fmaf(c3, wa.w, air);
    aiz = fmaf(c0, wb.x, aiz); aiz = fmaf(c1, wb.y, aiz); aiz = fmaf(c2, wb.z, aiz); aiz = fmaf(c3, wb.w, aiz);
    ain = fmaf(c0, wc.x, ain); ain = fmaf(c1, wc.y, ain); ain = fmaf(c2, wc.z, ain); ain = fmaf(c3, wc.w, ain);
    ahr = fmaf(h0, wd.x, ahr); ahr = fmaf(h1, wd.y, ahr); ahr = fmaf(h2, wd.z, ahr); ahr = fmaf(h3, wd.w, ahr);
    ahz = fmaf(h0, we.x, ahz); ahz = fmaf(h1, we.y, ahz); ahz = fmaf(h2, we.z, ahz); ahz = fmaf(h3, we.w, ahz);
    ahn = fmaf(h0, wf.x, ahn); ahn = fmaf(h1, wf.y, ahn); ahn = fmaf(h2, wf.z, ahn); ahn = fmaf(h3, wf.w, ahn);
  }
  float r = 1.f / (1.f + expf(-(air + ahr)));
  float z = 1.f / (1.f + expf(-(aiz + ahz)));
  float n = tanhf(fmaf(r, ahn, ain));
  float hp = hh[j];
  float hv = (1.f - z) * n + z * hp;
  h_new[(size_t)b * 512 + j] = hv;
  out_hid[(size_t)step * 65536 + (size_t)b * 512 + j] = (step < lens[b]) ? hv : 0.f;
}

// ---------------------------------------------------------------------------
// Logits + outputs-out + argmax (packed u64 atomicMax, first-index tie-break)
// grid 128: bt(16) x vt(8, 128 v each); block 256: 8b x 32v x 4r
// ---------------------------------------------------------------------------
__global__ __launch_bounds__(256) void logits_kernel(
    const float* __restrict__ Wfc, const float* __restrict__ bfc,
    const float* __restrict__ h_new, const int* __restrict__ lens,
    float* __restrict__ out_o, unsigned long long* __restrict__ packed,
    int step) {
  __shared__ float hs[8][512];
  int bi = blockIdx.x;
  int t = threadIdx.x;
  int bt = bi >> 3, vt = bi & 7;
  #pragma unroll
  for (int i = 0; i < 16; ++i) {
    int flat = i * 256 + t;
    int lb = flat >> 9, k = flat & 511;
    hs[lb][k] = h_new[(size_t)(bt * 8 + lb) * 512 + k];
  }
  __syncthreads();
  int lb = t >> 5, vv = t & 31;
  int b = bt * 8 + lb;
  const float* a = hs[lb];
  int run = step < lens[b];
  float bestv = -1e30f;
  int besti = 0;
  #pragma unroll
  for (int r = 0; r < 4; ++r) {
    int v = vt * 128 + r * 32 + vv;
    if (v < 1000) {
      float acc = bfc[v];
      const float* wrow = Wfc + (size_t)v * 512;
      #pragma unroll 4
      for (int k = 0; k < 512; k += 4) {
        float4 w = *(const float4*)(wrow + k);
        acc = fmaf(a[k + 0], w.x, acc);
        acc = fmaf(a[k + 1], w.y, acc);
        acc = fmaf(a[k + 2], w.z, acc);
        acc = fmaf(a[k + 3], w.w, acc);
      }
      out_o[(size_t)step * 128000 + (size_t)b * 1000 + v] = run ? acc : 0.f;
      if (acc > bestv) { bestv = acc; besti = v; }  // strict > keeps smallest v
    }
  }
  #pragma unroll
  for (int o = 16; o > 0; o >>= 1) {
    float ov = __shfl_xor(bestv, o);
    int oi = __shfl_xor(besti, o);
    if (ov > bestv || (ov == bestv && oi < besti)) { bestv = ov; besti = oi; }
  }
  if (vv == 0) {
    unsigned int fb = __float_as_uint(bestv);
    fb = (fb & 0x80000000u) ? ~fb : (fb | 0x80000000u);
    unsigned long long key =
        ((unsigned long long)fb << 32) | (unsigned long long)(0xFFFFFFFFu - (unsigned int)besti);
    atomicMax(packed + b, key);
  }
}

// ---------------------------------------------------------------------------
extern "C" void kernel_launch(void* const* d_in, const int* in_sizes, int n_in,
                              void* d_out, int out_size, void* d_ws, size_t ws_size,
                              hipStream_t stream) {
  const float* memory = (const float*)d_in[0];
  const float* emb    = (const float*)d_in[1];
  const float* Wq     = (const float*)d_in[2];
  const float* bq     = (const float*)d_in[3];
  const float* Wk     = (const float*)d_in[4];
  const float* bk     = (const float*)d_in[5];
  const float* Wv     = (const float*)d_in[6];
  const float* bv     = (const float*)d_in[7];
  const float* W_ih   = (const float*)d_in[8];
  const float* W_hh   = (const float*)d_in[9];
  const float* b_ih   = (const float*)d_in[10];
  const float* b_hh   = (const float*)d_in[11];
  const float* Wfc    = (const float*)d_in[12];
  const float* bfc    = (const float*)d_in[13];
  const int* lens     = (const int*)d_in[14];

  float* ws = (float*)d_ws;
  float* kp      = ws;                    // 128*8*512*64 = 33,554,432 f
  float* vp      = kp + 33554432;         // 33,554,432 f
  float* qb      = vp + 33554432;         // 65,536 f
  float* ctx     = qb + 65536;            // 65,536 f
  float* h0      = ctx + 65536;           // 65,536 f
  float* h1      = h0 + 65536;            // 65,536 f
  float* att_buf = h1 + 65536;            // 128*8*512 = 524,288 f
  unsigned long long* packed = (unsigned long long*)(att_buf + 524288);  // 128 u64

  float* out   = (float*)d_out;
  float* out_o = out;                  // 160*128*1000
  float* out_h = out + 20480000;       // 160*128*512
  float* out_s = out_h + 10485760;     // 160*128*512

  kv_proj<<<8192, 256, 0, stream>>>(memory, Wk, bk, kp);
  kv_proj<<<8192, 256, 0, stream>>>(memory, Wv, bv, vp);
  init_kernel<<<64, 256, 0, stream>>>(h0, packed);

  for (int t = 0; t < 160; ++t) {
    float* hp = (t & 1) ? h1 : h0;
    float* hn = (t & 1) ? h0 : h1;
    q_kernel<<<256, 256, 0, stream>>>(emb, Wq, bq, packed, hp, qb);
    attn_kernel<<<1024, 256, 0, stream>>>(kp, vp, qb, ctx, att_buf);
    gru_kernel<<<320, 256, 0, stream>>>(W_ih, W_hh, b_ih, b_hh, ctx, hp, hn,
                                        att_buf, lens, out_h, out_s, packed, t);
    logits_kernel<<<128, 256, 0, stream>>>(Wfc, bfc, hn, lens, out_o, packed, t);
  }
}

// Round 3
// 31610.590 us; speedup vs baseline: 1.3716x; 1.3716x over previous
//
#include <hip/hip_runtime.h>
#include <math.h>

// ---------------------------------------------------------------------------
// V projection precompute (fp32 SGEMM): out[b][h][m][d], row-major [m][d]
// grid: jt(8) + 8*(mt(8) + 8*b(128)); block 256 = 16x16 threads, 4x4 out each
// ---------------------------------------------------------------------------
__global__ __launch_bounds__(256) void kv_proj(
    const float* __restrict__ mem, const float* __restrict__ W,
    const float* __restrict__ bias, float* __restrict__ outp) {
  __shared__ float As[32][68];
  __shared__ float Bs[32][68];
  int gid = blockIdx.x;
  int jt = gid & 7, mt = (gid >> 3) & 7, b = gid >> 6;
  int t = threadIdx.x;
  int lm = t >> 2;
  int kq = (t & 3) * 8;
  int tx = t & 15, ty = t >> 4;
  float acc[4][4];
  #pragma unroll
  for (int r = 0; r < 4; ++r)
    #pragma unroll
    for (int c = 0; c < 4; ++c) acc[r][c] = 0.f;
  const float* Arow = mem + (size_t)(mt * 64 + lm) * 65536 + (size_t)b * 512 + kq;
  const float* Brow = W + (size_t)(jt * 64 + lm) * 512 + kq;
  for (int k0 = 0; k0 < 512; k0 += 32) {
    float4 a0 = *(const float4*)(Arow + k0);
    float4 a1 = *(const float4*)(Arow + k0 + 4);
    float4 b0 = *(const float4*)(Brow + k0);
    float4 b1 = *(const float4*)(Brow + k0 + 4);
    As[kq + 0][lm] = a0.x; As[kq + 1][lm] = a0.y; As[kq + 2][lm] = a0.z; As[kq + 3][lm] = a0.w;
    As[kq + 4][lm] = a1.x; As[kq + 5][lm] = a1.y; As[kq + 6][lm] = a1.z; As[kq + 7][lm] = a1.w;
    Bs[kq + 0][lm] = b0.x; Bs[kq + 1][lm] = b0.y; Bs[kq + 2][lm] = b0.z; Bs[kq + 3][lm] = b0.w;
    Bs[kq + 4][lm] = b1.x; Bs[kq + 5][lm] = b1.y; Bs[kq + 6][lm] = b1.z; Bs[kq + 7][lm] = b1.w;
    __syncthreads();
    #pragma unroll
    for (int k = 0; k < 32; ++k) {
      float4 av = *(const float4*)&As[k][ty * 4];
      float4 bv = *(const float4*)&Bs[k][tx * 4];
      float ar[4] = {av.x, av.y, av.z, av.w};
      float br[4] = {bv.x, bv.y, bv.z, bv.w};
      #pragma unroll
      for (int r = 0; r < 4; ++r)
        #pragma unroll
        for (int c = 0; c < 4; ++c) acc[r][c] = fmaf(ar[r], br[c], acc[r][c]);
    }
    __syncthreads();
  }
  float4 bb = *(const float4*)(bias + jt * 64 + tx * 4);
  #pragma unroll
  for (int r = 0; r < 4; ++r) {
    int m = mt * 64 + ty * 4 + r;
    float4 o;
    o.x = acc[r][0] + bb.x; o.y = acc[r][1] + bb.y;
    o.z = acc[r][2] + bb.z; o.w = acc[r][3] + bb.w;
    *(float4*)(outp + (((size_t)b * 8 + jt) * 512 + m) * 64 + tx * 4) = o;
  }
}

// ---------------------------------------------------------------------------
// K projection, TRANSPOSED output: out[b][h][d][m]  (d = head-local 0..63)
// Same tiling; scattered scalar stores (one-time cost, merged in L2).
// ---------------------------------------------------------------------------
__global__ __launch_bounds__(256) void kv_projT(
    const float* __restrict__ mem, const float* __restrict__ W,
    const float* __restrict__ bias, float* __restrict__ outp) {
  __shared__ float As[32][68];
  __shared__ float Bs[32][68];
  int gid = blockIdx.x;
  int jt = gid & 7, mt = (gid >> 3) & 7, b = gid >> 6;
  int t = threadIdx.x;
  int lm = t >> 2;
  int kq = (t & 3) * 8;
  int tx = t & 15, ty = t >> 4;
  float acc[4][4];
  #pragma unroll
  for (int r = 0; r < 4; ++r)
    #pragma unroll
    for (int c = 0; c < 4; ++c) acc[r][c] = 0.f;
  const float* Arow = mem + (size_t)(mt * 64 + lm) * 65536 + (size_t)b * 512 + kq;
  const float* Brow = W + (size_t)(jt * 64 + lm) * 512 + kq;
  for (int k0 = 0; k0 < 512; k0 += 32) {
    float4 a0 = *(const float4*)(Arow + k0);
    float4 a1 = *(const float4*)(Arow + k0 + 4);
    float4 b0 = *(const float4*)(Brow + k0);
    float4 b1 = *(const float4*)(Brow + k0 + 4);
    As[kq + 0][lm] = a0.x; As[kq + 1][lm] = a0.y; As[kq + 2][lm] = a0.z; As[kq + 3][lm] = a0.w;
    As[kq + 4][lm] = a1.x; As[kq + 5][lm] = a1.y; As[kq + 6][lm] = a1.z; As[kq + 7][lm] = a1.w;
    Bs[kq + 0][lm] = b0.x; Bs[kq + 1][lm] = b0.y; Bs[kq + 2][lm] = b0.z; Bs[kq + 3][lm] = b0.w;
    Bs[kq + 4][lm] = b1.x; Bs[kq + 5][lm] = b1.y; Bs[kq + 6][lm] = b1.z; Bs[kq + 7][lm] = b1.w;
    __syncthreads();
    #pragma unroll
    for (int k = 0; k < 32; ++k) {
      float4 av = *(const float4*)&As[k][ty * 4];
      float4 bv = *(const float4*)&Bs[k][tx * 4];
      float ar[4] = {av.x, av.y, av.z, av.w};
      float br[4] = {bv.x, bv.y, bv.z, bv.w};
      #pragma unroll
      for (int r = 0; r < 4; ++r)
        #pragma unroll
        for (int c = 0; c < 4; ++c) acc[r][c] = fmaf(ar[r], br[c], acc[r][c]);
    }
    __syncthreads();
  }
  float4 bb = *(const float4*)(bias + jt * 64 + tx * 4);
  float bc[4] = {bb.x, bb.y, bb.z, bb.w};
  #pragma unroll
  for (int r = 0; r < 4; ++r) {
    int m = mt * 64 + ty * 4 + r;
    #pragma unroll
    for (int c = 0; c < 4; ++c) {
      int d = tx * 4 + c;  // head-local dim
      outp[((size_t)(b * 8 + jt) * 64 + d) * 512 + m] = acc[r][c] + bc[c];
    }
  }
}

// ---------------------------------------------------------------------------
__global__ __launch_bounds__(256) void init_kernel(float* __restrict__ h0,
                                                   unsigned long long* __restrict__ packed) {
  int t = threadIdx.x + blockIdx.x * blockDim.x;
  for (int i = t; i < 128 * 512; i += blockDim.x * gridDim.x) h0[i] = 0.f;
  if (t < 128) packed[t] = (0x80000000ull << 32) | 0xFFFFFFFFull;  // val 0.0, idx 0
}

// ---------------------------------------------------------------------------
// Fused q-projection + attention. One block per (b, head).
//   q_j = bq[j] + [emb[tok_b], h_prev_b] . Wq[j,:]   (only this head's 64 j)
//   scores from K^T [d][m] (fully coalesced float2 along m)
//   ctx from V [m][d] (4 rows x 256B contiguous per instruction)
// ---------------------------------------------------------------------------
__global__ __launch_bounds__(256) void attn_fused(
    const float* __restrict__ kpT, const float* __restrict__ vp,
    const float* __restrict__ emb, const float* __restrict__ Wq,
    const float* __restrict__ bq, const unsigned long long* __restrict__ packed,
    const float* __restrict__ h_prev, float* __restrict__ ctx,
    float* __restrict__ att_buf) {
  int b = blockIdx.x >> 3, hd = blockIdx.x & 7;
  __shared__ float act[1024];
  __shared__ float qs[64];
  __shared__ float att[512];
  __shared__ __align__(16) float red[16][68];
  __shared__ float rmax[4], rsum[4];
  __shared__ int tok_s;
  int t = threadIdx.x;
  if (t == 0) tok_s = (int)(0xFFFFFFFFu - (unsigned int)(packed[b] & 0xFFFFFFFFull));
  __syncthreads();
  int tok = tok_s;
  act[t]       = emb[(size_t)tok * 512 + t];
  act[256 + t] = emb[(size_t)tok * 512 + 256 + t];
  act[512 + t] = h_prev[(size_t)b * 512 + t];
  act[768 + t] = h_prev[(size_t)b * 512 + 256 + t];
  __syncthreads();

  // --- q for this head's 64 dims: thread = (j_local = t>>2, kc = t&3) ---
  {
    int jl = t >> 2, kc = t & 3;
    const float* wrow = Wq + (size_t)(hd * 64 + jl) * 1024 + kc * 256;
    const float* a = act + kc * 256;
    float p = 0.f;
    #pragma unroll 8
    for (int i = 0; i < 256; i += 4) {
      float4 w = *(const float4*)(wrow + i);
      p = fmaf(a[i + 0], w.x, p);
      p = fmaf(a[i + 1], w.y, p);
      p = fmaf(a[i + 2], w.z, p);
      p = fmaf(a[i + 3], w.w, p);
    }
    p += __shfl_xor(p, 1);
    p += __shfl_xor(p, 2);
    if (kc == 0) qs[jl] = p + bq[hd * 64 + jl];
  }
  __syncthreads();

  // --- scores: thread t owns m = 2t, 2t+1; K^T stream fully coalesced ---
  const float* Kb = kpT + (size_t)(b * 8 + hd) * 32768;  // [64][512]
  float s0 = 0.f, s1 = 0.f;
  {
    int m2 = 2 * t;
    #pragma unroll 8
    for (int d = 0; d < 64; ++d) {
      float2 kk = *(const float2*)(Kb + (size_t)d * 512 + m2);
      float qd = qs[d];
      s0 = fmaf(qd, kk.x, s0);
      s1 = fmaf(qd, kk.y, s1);
    }
    s0 *= 0.125f;  // 1/sqrt(64)
    s1 *= 0.125f;
  }
  // --- softmax over 512 ---
  float mx = fmaxf(s0, s1);
  #pragma unroll
  for (int o = 32; o > 0; o >>= 1) mx = fmaxf(mx, __shfl_xor(mx, o));
  if ((t & 63) == 0) rmax[t >> 6] = mx;
  __syncthreads();
  mx = fmaxf(fmaxf(rmax[0], rmax[1]), fmaxf(rmax[2], rmax[3]));
  float e0 = expf(s0 - mx), e1 = expf(s1 - mx);
  float sm = e0 + e1;
  #pragma unroll
  for (int o = 32; o > 0; o >>= 1) sm += __shfl_xor(sm, o);
  if ((t & 63) == 0) rsum[t >> 6] = sm;
  __syncthreads();
  sm = rsum[0] + rsum[1] + rsum[2] + rsum[3];
  float inv = 1.f / sm;
  float a0 = e0 * inv, a1 = e1 * inv;
  att[2 * t] = a0;
  att[2 * t + 1] = a1;
  *(float2*)(att_buf + (size_t)(b * 8 + hd) * 512 + 2 * t) = make_float2(a0, a1);
  __syncthreads();

  // --- ctx: thread = (row-group g = t>>4, d-slice = (t&15)*4) ---
  const float* Vb = vp + (size_t)(b * 8 + hd) * 32768;  // [512][64]
  {
    int dsl = (t & 15) * 4, g = t >> 4;
    float c0 = 0.f, c1 = 0.f, c2 = 0.f, c3 = 0.f;
    #pragma unroll 4
    for (int m = g; m < 512; m += 16) {
      float4 vv = *(const float4*)(Vb + (size_t)m * 64 + dsl);
      float am = att[m];
      c0 = fmaf(am, vv.x, c0);
      c1 = fmaf(am, vv.y, c1);
      c2 = fmaf(am, vv.z, c2);
      c3 = fmaf(am, vv.w, c3);
    }
    red[g][dsl + 0] = c0;
    red[g][dsl + 1] = c1;
    red[g][dsl + 2] = c2;
    red[g][dsl + 3] = c3;
  }
  __syncthreads();
  if (t < 64) {
    float cc = 0.f;
    #pragma unroll
    for (int g2 = 0; g2 < 16; ++g2) cc += red[g2][t];
    ctx[(size_t)b * 512 + hd * 64 + t] = cc;
  }
}

// ---------------------------------------------------------------------------
// GRU + hiddens-out; extra blocks: scores-out (mean over heads) + packed reset
// grid 320: [0,256) GRU (bt16 x jt16), [256,320) scores
// ---------------------------------------------------------------------------
__global__ __launch_bounds__(256) void gru_kernel(
    const float* __restrict__ W_ih, const float* __restrict__ W_hh,
    const float* __restrict__ b_ih, const float* __restrict__ b_hh,
    const float* __restrict__ ctx, const float* __restrict__ h_prev,
    float* __restrict__ h_new, const float* __restrict__ att_buf,
    const int* __restrict__ lens, float* __restrict__ out_hid,
    float* __restrict__ out_sc, unsigned long long* __restrict__ packed,
    int step) {
  __shared__ float cs[8][512];
  __shared__ float hs[8][512];
  int bi = blockIdx.x;
  int t = threadIdx.x;
  if (bi >= 256) {
    int sb = bi - 256;  // 0..63
    if (sb == 0 && t < 128) packed[t] = 0ull;  // reset for this step's logits atomics
    #pragma unroll
    for (int i = 0; i < 4; ++i) {
      int flat = sb * 1024 + i * 256 + t;  // over b*512+m
      int bb = flat >> 9, m = flat & 511;
      float sum = 0.f;
      #pragma unroll
      for (int h = 0; h < 8; ++h) sum += att_buf[(size_t)(bb * 8 + h) * 512 + m];
      float val = sum * 0.125f;
      out_sc[(size_t)step * 65536 + flat] = (step < lens[bb]) ? val : 0.f;
    }
    return;
  }
  int bt = bi >> 4, jt = bi & 15;
  #pragma unroll
  for (int i = 0; i < 16; ++i) {
    int flat = i * 256 + t;
    int lb = flat >> 9, k = flat & 511;
    cs[lb][k] = ctx[(size_t)(bt * 8 + lb) * 512 + k];
    hs[lb][k] = h_prev[(size_t)(bt * 8 + lb) * 512 + k];
  }
  __syncthreads();
  int lb = t >> 5, j = (jt << 5) + (t & 31);
  int b = bt * 8 + lb;
  float air = b_ih[j], aiz = b_ih[512 + j], ain = b_ih[1024 + j];
  float ahr = b_hh[j], ahz = b_hh[512 + j], ahn = b_hh[1024 + j];
  const float* c = cs[lb];
  const float* hh = hs[lb];
  const float* wi0 = W_ih + (size_t)j * 512;
  const float* wi1 = W_ih + (size_t)(512 + j) * 512;
  const float* wi2 = W_ih + (size_t)(1024 + j) * 512;
  const float* wh0 = W_hh + (size_t)j * 512;
  const float* wh1 = W_hh + (size_t)(512 + j) * 512;
  const float* wh2 = W_hh + (size_t)(1024 + j) * 512;
  #pragma unroll 2
  for (int k = 0; k < 512; k += 4) {
    float4 wa = *(const float4*)(wi0 + k);
    float4 wb = *(const float4*)(wi1 + k);
    float4 wc = *(const float4*)(wi2 + k);
    float4 wd = *(const float4*)(wh0 + k);
    float4 we = *(const float4*)(wh1 + k);
    float4 wf = *(const float4*)(wh2 + k);
    float c0 = c[k], c1 = c[k + 1], c2 = c[k + 2], c3 = c[k + 3];
    float h0 = hh[k], h1 = hh[k + 1], h2 = hh[k + 2], h3 = hh[k + 3];
    air = fmaf(c0, wa.x, air); air = fmaf(c1, wa.y, air); air = fmaf(c2, wa.z, air); air = fmaf(c3, wa.w, air);
    aiz = fmaf(c0, wb.x, aiz); aiz = fmaf(c1, wb.y, aiz); aiz = fmaf(c2, wb.z, aiz); aiz = fmaf(c3, wb.w, aiz);
    ain = fmaf(c0, wc.x, ain); ain = fmaf(c1, wc.y, ain); ain = fmaf(c2, wc.z, ain); ain = fmaf(c3, wc.w, ain);
    ahr = fmaf(h0, wd.x, ahr); ahr = fmaf(h1, wd.y, ahr); ahr = fmaf(h2, wd.z, ahr); ahr = fmaf(h3, wd.w, ahr);
    ahz = fmaf(h0, we.x, ahz); ahz = fmaf(h1, we.y, ahz); ahz = fmaf(h2, we.z, ahz); ahz = fmaf(h3, we.w, ahz);
    ahn = fmaf(h0, wf.x, ahn); ahn = fmaf(h1, wf.y, ahn); ahn = fmaf(h2, wf.z, ahn); ahn = fmaf(h3, wf.w, ahn);
  }
  float r = 1.f / (1.f + expf(-(air + ahr)));
  float z = 1.f / (1.f + expf(-(aiz + ahz)));
  float n = tanhf(fmaf(r, ahn, ain));
  float hp = hh[j];
  float hv = (1.f - z) * n + z * hp;
  h_new[(size_t)b * 512 + j] = hv;
  out_hid[(size_t)step * 65536 + (size_t)b * 512 + j] = (step < lens[b]) ? hv : 0.f;
}

// ---------------------------------------------------------------------------
// Logits + outputs-out + argmax (packed u64 atomicMax, first-index tie-break)
// grid 256: bt(16) x vt(16, 64 v each); block 256: 8b x 32v x 2r
// ---------------------------------------------------------------------------
__global__ __launch_bounds__(256) void logits_kernel(
    const float* __restrict__ Wfc, const float* __restrict__ bfc,
    const float* __restrict__ h_new, const int* __restrict__ lens,
    float* __restrict__ out_o, unsigned long long* __restrict__ packed,
    int step) {
  __shared__ float hs[8][512];
  int bi = blockIdx.x;
  int t = threadIdx.x;
  int bt = bi >> 4, vt = bi & 15;
  #pragma unroll
  for (int i = 0; i < 16; ++i) {
    int flat = i * 256 + t;
    int lb = flat >> 9, k = flat & 511;
    hs[lb][k] = h_new[(size_t)(bt * 8 + lb) * 512 + k];
  }
  __syncthreads();
  int lb = t >> 5, vv = t & 31;
  int b = bt * 8 + lb;
  const float* a = hs[lb];
  int run = step < lens[b];
  float bestv = -1e30f;
  int besti = 0;
  #pragma unroll
  for (int r = 0; r < 2; ++r) {
    int v = vt * 64 + r * 32 + vv;
    if (v < 1000) {
      float acc = bfc[v];
      const float* wrow = Wfc + (size_t)v * 512;
      #pragma unroll 4
      for (int k = 0; k < 512; k += 4) {
        float4 w = *(const float4*)(wrow + k);
        acc = fmaf(a[k + 0], w.x, acc);
        acc = fmaf(a[k + 1], w.y, acc);
        acc = fmaf(a[k + 2], w.z, acc);
        acc = fmaf(a[k + 3], w.w, acc);
      }
      out_o[(size_t)step * 128000 + (size_t)b * 1000 + v] = run ? acc : 0.f;
      if (acc > bestv) { bestv = acc; besti = v; }  // strict > keeps smallest v
    }
  }
  #pragma unroll
  for (int o = 16; o > 0; o >>= 1) {
    float ov = __shfl_xor(bestv, o);
    int oi = __shfl_xor(besti, o);
    if (ov > bestv || (ov == bestv && oi < besti)) { bestv = ov; besti = oi; }
  }
  if (vv == 0) {
    unsigned int fb = __float_as_uint(bestv);
    fb = (fb & 0x80000000u) ? ~fb : (fb | 0x80000000u);
    unsigned long long key =
        ((unsigned long long)fb << 32) | (unsigned long long)(0xFFFFFFFFu - (unsigned int)besti);
    atomicMax(packed + b, key);
  }
}

// ---------------------------------------------------------------------------
extern "C" void kernel_launch(void* const* d_in, const int* in_sizes, int n_in,
                              void* d_out, int out_size, void* d_ws, size_t ws_size,
                              hipStream_t stream) {
  const float* memory = (const float*)d_in[0];
  const float* emb    = (const float*)d_in[1];
  const float* Wq     = (const float*)d_in[2];
  const float* bq     = (const float*)d_in[3];
  const float* Wk     = (const float*)d_in[4];
  const float* bk     = (const float*)d_in[5];
  const float* Wv     = (const float*)d_in[6];
  const float* bv     = (const float*)d_in[7];
  const float* W_ih   = (const float*)d_in[8];
  const float* W_hh   = (const float*)d_in[9];
  const float* b_ih   = (const float*)d_in[10];
  const float* b_hh   = (const float*)d_in[11];
  const float* Wfc    = (const float*)d_in[12];
  const float* bfc    = (const float*)d_in[13];
  const int* lens     = (const int*)d_in[14];

  float* ws = (float*)d_ws;
  float* kpT     = ws;                    // 128*8*64*512 = 33,554,432 f  [b][h][d][m]
  float* vp      = kpT + 33554432;        // 33,554,432 f                [b][h][m][d]
  float* ctx     = vp + 33554432;         // 65,536 f
  float* h0      = ctx + 65536;           // 65,536 f
  float* h1      = h0 + 65536;            // 65,536 f
  float* att_buf = h1 + 65536;            // 128*8*512 = 524,288 f
  unsigned long long* packed = (unsigned long long*)(att_buf + 524288);  // 128 u64

  float* out   = (float*)d_out;
  float* out_o = out;                  // 160*128*1000
  float* out_h = out + 20480000;       // 160*128*512
  float* out_s = out_h + 10485760;     // 160*128*512

  kv_projT<<<8192, 256, 0, stream>>>(memory, Wk, bk, kpT);
  kv_proj<<<8192, 256, 0, stream>>>(memory, Wv, bv, vp);
  init_kernel<<<64, 256, 0, stream>>>(h0, packed);

  for (int t = 0; t < 160; ++t) {
    float* hp = (t & 1) ? h1 : h0;
    float* hn = (t & 1) ? h0 : h1;
    attn_fused<<<1024, 256, 0, stream>>>(kpT, vp, emb, Wq, bq, packed, hp, ctx, att_buf);
    gru_kernel<<<320, 256, 0, stream>>>(W_ih, W_hh, b_ih, b_hh, ctx, hp, hn,
                                        att_buf, lens, out_h, out_s, packed, t);
    logits_kernel<<<256, 256, 0, stream>>>(Wfc, bfc, hn, lens, out_o, packed, t);
  }
}